// Round 1
// baseline (239.390 us; speedup 1.0000x reference)
//
#include <hip/hip_runtime.h>
#include <stdint.h>

// Problem constants (fixed by reference):
//   N=4 batches, C=256 channels, S=16 slices, H*W=1024, K1=S*C=4096, 3 layers.
#define CC   256
#define SSL  16
#define NB   4
#define HWP  1024
#define K1   4096
#define EPSV 1e-5f
#define PART (12 * CC * CC)   // floats per split-K partial block (12 = 3 layers * 4 batches)

// ---------------------------------------------------------------------------
// Kernel 1: per-(n, k, b) flags.
// flag = 2 if all 16 rows of slice k have m[row][b] > 0 ("use m")
//        1 if any (but not all)                         ("use max(m,0)")
//        0 otherwise                                    ("use 0")
// Grid: 64 blocks (n*16+k), 256 threads (b). Coalesced row reads.
__global__ __launch_bounds__(256) void flags_kernel(const float* __restrict__ adj,
                                                    uint8_t* __restrict__ flags) {
    const int nk = blockIdx.x;            // n*16 + k
    const int n = nk >> 4, k = nk & 15;
    const int b = threadIdx.x;
    const float* m = adj + (size_t)n * CC * CC;
    bool allp = true, anyp = false;
#pragma unroll
    for (int i = 0; i < 16; ++i) {
        float v = m[(size_t)(k * 16 + i) * CC + b];
        bool p = v > 0.0f;
        allp = allp && p;
        anyp = anyp || p;
    }
    flags[(size_t)nk * CC + b] = allp ? (uint8_t)2 : (anyp ? (uint8_t)1 : (uint8_t)0);
}

// ---------------------------------------------------------------------------
// Kernel 2: W_eff partial GEMM (fp32).
//   W_eff[l,n][o,b] = sum_kk conv_w[l][o,kk] * mss[n][kk,b],  kk = k*256 + a,
//   mss[kk,b] = sel(flag[n,k,b], adj[n][a,b])   (applied at B-tile staging).
// Tile 64x64, BK=16, 4x4 microtile, 256 threads. Split-K=4: blockIdx.z picks
// a 1024-wide K chunk; partials stored separately (summed by layer_kernel).
// Grid: (16 tiles, 12 l*n, 4 splits).
__global__ __launch_bounds__(256) void weff_kernel(const float* __restrict__ conv_w,
                                                   const float* __restrict__ adj,
                                                   const uint8_t* __restrict__ flags,
                                                   float* __restrict__ wpart) {
    const int tile = blockIdx.x;
    const int ln   = blockIdx.y;          // l*4 + n
    const int sp   = blockIdx.z;          // split-K index
    const int l = ln >> 2, n = ln & 3;
    const int trow = (tile >> 2) * 64;    // output row (o) tile
    const int tcol = (tile & 3) * 64;     // output col (b) tile

    const float*   A  = conv_w + (size_t)l * CC * K1;   // [256 o][4096 kk]
    const float*   M  = adj + (size_t)n * CC * CC;      // [256 a][256 b]
    const uint8_t* FL = flags + (size_t)n * SSL * CC;   // [16 k][256 b]

    __shared__ float As[16][68];   // [kk_local][row]  (transposed for float4 frag reads)
    __shared__ float Bs[16][68];   // [kk_local][col]

    const int t  = threadIdx.x;
    const int tx = t & 15, ty = t >> 4;          // 16x16 thread grid, 4x4 micro
    const int ar = t >> 2, ac4 = (t & 3) * 4;    // A staging: row, col-chunk
    const int br = t >> 4, bc4 = (t & 15) * 4;   // B staging: k-row, col-chunk

    float acc[4][4] = {};

    const int kt0 = sp * 64;                     // 256 K-tiles of 16, /4 splits
    for (int kt = kt0; kt < kt0 + 64; ++kt) {
        // A tile: 64 rows x 16 k, float4 per thread (coalesced in 64B chunks)
        float4 av = *(const float4*)(A + (size_t)(trow + ar) * K1 + kt * 16 + ac4);
        // B tile: kk = kt*16 + br  ->  k = kt>>4 (constant in tile), a = (kt&15)*16 + br
        const int k  = kt >> 4;
        const int a0 = (kt & 15) * 16;
        float4 mv = *(const float4*)(M + (size_t)(a0 + br) * CC + tcol + bc4);
        uchar4 fv = *(const uchar4*)(FL + (size_t)k * CC + tcol + bc4);
        float4 bv;
        bv.x = (fv.x == 2) ? mv.x : ((fv.x == 1) ? fmaxf(mv.x, 0.f) : 0.f);
        bv.y = (fv.y == 2) ? mv.y : ((fv.y == 1) ? fmaxf(mv.y, 0.f) : 0.f);
        bv.z = (fv.z == 2) ? mv.z : ((fv.z == 1) ? fmaxf(mv.z, 0.f) : 0.f);
        bv.w = (fv.w == 2) ? mv.w : ((fv.w == 1) ? fmaxf(mv.w, 0.f) : 0.f);

        __syncthreads();
        As[ac4 + 0][ar] = av.x;
        As[ac4 + 1][ar] = av.y;
        As[ac4 + 2][ar] = av.z;
        As[ac4 + 3][ar] = av.w;
        *(float4*)&Bs[br][bc4] = bv;
        __syncthreads();

#pragma unroll
        for (int kk = 0; kk < 16; ++kk) {
            float4 af = *(const float4*)&As[kk][ty * 4];   // 4 rows (broadcast x16 lanes)
            float4 bf = *(const float4*)&Bs[kk][tx * 4];   // 4 cols (broadcast x4 lanes)
            float a_[4] = {af.x, af.y, af.z, af.w};
            float b_[4] = {bf.x, bf.y, bf.z, bf.w};
#pragma unroll
            for (int i = 0; i < 4; ++i)
#pragma unroll
                for (int j = 0; j < 4; ++j)
                    acc[i][j] = fmaf(a_[i], b_[j], acc[i][j]);
        }
    }

    // Store raw partial (scale/bias folded later in layer_kernel).
    float* W = wpart + (size_t)sp * PART + (size_t)ln * CC * CC;
#pragma unroll
    for (int i = 0; i < 4; ++i) {
        const int o = trow + ty * 4 + i;
        float4 v = {acc[i][0], acc[i][1], acc[i][2], acc[i][3]};
        *(float4*)(W + (size_t)o * CC + tcol + tx * 4) = v;
    }
}

// ---------------------------------------------------------------------------
// Kernel 3: layer GEMM + BN + ReLU (fp32).
//   y[n][o,p] = relu( scale[o] * (W_eff[l,n] @ x[n])[o,p] + bias2[o] )
//   scale = gamma*rsqrt(var+eps); bias2 = scale*(conv_b-mean)+beta.
// A-load sums the 4 split-K partials and applies scale (linear, so valid).
// Tile 64x64 over [256 o x 1024 p], K=256. Grid: (64 tiles, 4 n).
__global__ __launch_bounds__(256) void layer_kernel(const float* __restrict__ wl,    // + l*4*CC*CC
                                                    const float* __restrict__ xin,   // [NB][CC][HWP]
                                                    const float* __restrict__ convb_l,
                                                    const float* __restrict__ gamma_l,
                                                    const float* __restrict__ beta_l,
                                                    const float* __restrict__ mean_l,
                                                    const float* __restrict__ var_l,
                                                    float* __restrict__ out) {
    const int n    = blockIdx.y;
    const int tile = blockIdx.x;
    const int trow = (tile >> 4) * 64;    // o tile (256/64 = 4)
    const int pcol = (tile & 15) * 64;    // p tile (1024/64 = 16)

    const float* A = wl + (size_t)n * CC * CC;       // W_eff partial 0 for (l,n)
    const float* B = xin + (size_t)n * CC * HWP;     // x[n]

    __shared__ float As[16][68];
    __shared__ float Bs[16][68];

    const int t  = threadIdx.x;
    const int tx = t & 15, ty = t >> 4;
    const int ar = t >> 2, ac4 = (t & 3) * 4;
    const int br = t >> 4, bc4 = (t & 15) * 4;

    const int arow = trow + ar;
    const float sA = gamma_l[arow] * rsqrtf(var_l[arow] + EPSV);  // row scale, hoisted

    float acc[4][4] = {};

    for (int kt = 0; kt < CC / 16; ++kt) {
        const float* Ap = A + (size_t)arow * CC + kt * 16 + ac4;
        float4 a0 = *(const float4*)(Ap);
        float4 a1 = *(const float4*)(Ap + (size_t)PART);
        float4 a2 = *(const float4*)(Ap + 2 * (size_t)PART);
        float4 a3 = *(const float4*)(Ap + 3 * (size_t)PART);
        float4 av;
        av.x = (a0.x + a1.x + a2.x + a3.x) * sA;
        av.y = (a0.y + a1.y + a2.y + a3.y) * sA;
        av.z = (a0.z + a1.z + a2.z + a3.z) * sA;
        av.w = (a0.w + a1.w + a2.w + a3.w) * sA;
        float4 bv = *(const float4*)(B + (size_t)(kt * 16 + br) * HWP + pcol + bc4);

        __syncthreads();
        As[ac4 + 0][ar] = av.x;
        As[ac4 + 1][ar] = av.y;
        As[ac4 + 2][ar] = av.z;
        As[ac4 + 3][ar] = av.w;
        *(float4*)&Bs[br][bc4] = bv;
        __syncthreads();

#pragma unroll
        for (int kk = 0; kk < 16; ++kk) {
            float4 af = *(const float4*)&As[kk][ty * 4];
            float4 bf = *(const float4*)&Bs[kk][tx * 4];
            float a_[4] = {af.x, af.y, af.z, af.w};
            float b_[4] = {bf.x, bf.y, bf.z, bf.w};
#pragma unroll
            for (int i = 0; i < 4; ++i)
#pragma unroll
                for (int j = 0; j < 4; ++j)
                    acc[i][j] = fmaf(a_[i], b_[j], acc[i][j]);
        }
    }

#pragma unroll
    for (int i = 0; i < 4; ++i) {
        const int o = trow + ty * 4 + i;
        const float sc = gamma_l[o] * rsqrtf(var_l[o] + EPSV);
        const float b2 = sc * (convb_l[o] - mean_l[o]) + beta_l[o];
        float4 v;
        v.x = fmaxf(acc[i][0] + b2, 0.f);
        v.y = fmaxf(acc[i][1] + b2, 0.f);
        v.z = fmaxf(acc[i][2] + b2, 0.f);
        v.w = fmaxf(acc[i][3] + b2, 0.f);
        *(float4*)(out + ((size_t)n * CC + o) * HWP + pcol + tx * 4) = v;
    }
}

// ---------------------------------------------------------------------------
extern "C" void kernel_launch(void* const* d_in, const int* in_sizes, int n_in,
                              void* d_out, int out_size, void* d_ws, size_t ws_size,
                              hipStream_t stream) {
    const float* feats  = (const float*)d_in[0];
    const float* adj    = (const float*)d_in[1];
    const float* conv_w = (const float*)d_in[2];
    const float* conv_b = (const float*)d_in[3];
    const float* gamma  = (const float*)d_in[4];
    const float* beta   = (const float*)d_in[5];
    const float* mean   = (const float*)d_in[6];
    const float* var    = (const float*)d_in[7];
    float* out = (float*)d_out;

    // Workspace layout: [0, 16KB) flags (uint8), [64KB, 64KB + 4*PART*4B) W_eff partials.
    uint8_t* flags = (uint8_t*)d_ws;
    float*   wpart = (float*)((char*)d_ws + 65536);

    flags_kernel<<<NB * SSL, CC, 0, stream>>>(adj, flags);
    weff_kernel<<<dim3(16, 12, 4), 256, 0, stream>>>(conv_w, adj, flags, wpart);

    for (int l = 0; l < 3; ++l) {
        const float* xin = (l == 0) ? feats : out + (size_t)(l - 1) * NB * CC * HWP;
        layer_kernel<<<dim3(64, NB), 256, 0, stream>>>(
            wpart + (size_t)l * NB * CC * CC, xin,
            conv_b + l * CC, gamma + l * CC, beta + l * CC, mean + l * CC, var + l * CC,
            out + (size_t)l * NB * CC * HWP);
    }
}

// Round 2
// 131.428 us; speedup vs baseline: 1.8215x; 1.8215x over previous
//
#include <hip/hip_runtime.h>
#include <stdint.h>

// N=4 batches, C=256, S=16, H*W=1024, K1=S*C=4096, 3 layers.
#define CC   256
#define SSL  16
#define NB   4
#define HWP  1024
#define K1   4096
#define EPSV 1e-5f

typedef __attribute__((ext_vector_type(8))) short bf16x8;
typedef __attribute__((ext_vector_type(4))) float f32x4;

__device__ __forceinline__ ushort f2bf(float f) {
    uint32_t u = __float_as_uint(f);
    uint32_t r = (u + 0x7FFFu + ((u >> 16) & 1u)) >> 16;   // RNE
    return (ushort)r;
}

// ---------------------------------------------------------------------------
// flags[n][k][b]: 2 = all 16 rows of slice k positive at col b, 1 = any, 0 = none.
__global__ __launch_bounds__(256) void flags_kernel(const float* __restrict__ adj,
                                                    uint8_t* __restrict__ flags) {
    const int nk = blockIdx.x;            // n*16 + k
    const int n = nk >> 4, k = nk & 15;
    const int b = threadIdx.x;
    const float* m = adj + (size_t)n * CC * CC;
    bool allp = true, anyp = false;
#pragma unroll
    for (int i = 0; i < 16; ++i) {
        float v = m[(size_t)(k * 16 + i) * CC + b];
        bool p = v > 0.0f;
        allp = allp && p;
        anyp = anyp || p;
    }
    flags[(size_t)nk * CC + b] = allp ? (uint8_t)2 : (anyp ? (uint8_t)1 : (uint8_t)0);
}

// ---------------------------------------------------------------------------
// conv_w fp32 -> bf16, straight copy. 3*256*4096 elems, 4/thread.
__global__ __launch_bounds__(256) void convw_bf16_kernel(const float* __restrict__ w,
                                                         ushort* __restrict__ wb) {
    const int idx = (blockIdx.x * 256 + threadIdx.x) * 4;
    float4 v = *(const float4*)(w + idx);
    ushort4 o = {f2bf(v.x), f2bf(v.y), f2bf(v.z), f2bf(v.w)};
    *(ushort4*)(wb + idx) = o;
}

// ---------------------------------------------------------------------------
// msst[n][b][k*256+a] = bf16( sel(flag[n,k,b], m[n,a,b]) )  — B^T layout (K-contig).
// Block: one (n, 64a x 64b) tile; LDS transpose; 16 gated copies along k.
__global__ __launch_bounds__(256) void msst_kernel(const float* __restrict__ adj,
                                                   const uint8_t* __restrict__ flags,
                                                   ushort* __restrict__ msst) {
    const int n = blockIdx.y;
    const int at = blockIdx.x >> 2, bt = blockIdx.x & 3;
    const int a0 = at * 64, b0 = bt * 64;
    const float* m = adj + (size_t)n * CC * CC;
    __shared__ float Ms[64][68];
    __shared__ uint8_t Fl[16][64];
    const int t = threadIdx.x;
    {
        const int ar = t >> 2, bq = (t & 3) * 16;
        const float* src = m + (size_t)(a0 + ar) * CC + b0 + bq;
#pragma unroll
        for (int i = 0; i < 4; ++i)
            *(float4*)&Ms[ar][bq + i * 4] = *(const float4*)(src + i * 4);
        const int k = t >> 4, b4 = (t & 15) * 4;
        *(uchar4*)&Fl[k][b4] = *(const uchar4*)(flags + (size_t)(n * SSL + k) * CC + b0 + b4);
    }
    __syncthreads();
    const int bl = t >> 2, ac = (t & 3) * 16;
    // Precompute bf16(m) and bf16(max(m,0)) for this thread's 16 a-values.
    ushort bx[16], bp[16];
#pragma unroll
    for (int i = 0; i < 16; ++i) {
        float x = Ms[ac + i][bl];
        bx[i] = f2bf(x);
        bp[i] = f2bf(fmaxf(x, 0.0f));
    }
    ushort* dst = msst + ((size_t)(n * CC + b0 + bl)) * K1 + a0 + ac;
#pragma unroll
    for (int k = 0; k < 16; ++k) {
        const uint8_t f = Fl[k][bl];
        ushort* dk = dst + k * CC;
#pragma unroll
        for (int a4 = 0; a4 < 4; ++a4) {
            ushort4 o;
            o.x = (f == 2) ? bx[a4 * 4 + 0] : ((f == 1) ? bp[a4 * 4 + 0] : (ushort)0);
            o.y = (f == 2) ? bx[a4 * 4 + 1] : ((f == 1) ? bp[a4 * 4 + 1] : (ushort)0);
            o.z = (f == 2) ? bx[a4 * 4 + 2] : ((f == 1) ? bp[a4 * 4 + 2] : (ushort)0);
            o.w = (f == 2) ? bx[a4 * 4 + 3] : ((f == 1) ? bp[a4 * 4 + 3] : (ushort)0);
            *(ushort4*)(dk + a4 * 4) = o;
        }
    }
}

// ---------------------------------------------------------------------------
// feats [n][c][p] fp32 -> fT [n][p][c] bf16 (layer-A layout, K=c contiguous).
__global__ __launch_bounds__(256) void featsT_kernel(const float* __restrict__ feats,
                                                     ushort* __restrict__ fT) {
    const int n = blockIdx.y;
    const int ct = blockIdx.x >> 4, pt = blockIdx.x & 15;
    const int c0 = ct * 64, p0 = pt * 64;
    const float* src = feats + ((size_t)n * CC + c0) * HWP + p0;
    __shared__ float Ts[64][68];
    const int t = threadIdx.x;
    const int cr = t >> 2, pq = (t & 3) * 16;
#pragma unroll
    for (int i = 0; i < 4; ++i)
        *(float4*)&Ts[cr][pq + i * 4] = *(const float4*)(src + (size_t)cr * HWP + pq + i * 4);
    __syncthreads();
    const int pl = t >> 2, cc0 = (t & 3) * 16;
    ushort* dst = fT + ((size_t)n * HWP + p0 + pl) * CC + c0 + cc0;
#pragma unroll
    for (int a4 = 0; a4 < 4; ++a4) {
        ushort4 o;
        o.x = f2bf(Ts[cc0 + a4 * 4 + 0][pl]);
        o.y = f2bf(Ts[cc0 + a4 * 4 + 1][pl]);
        o.z = f2bf(Ts[cc0 + a4 * 4 + 2][pl]);
        o.w = f2bf(Ts[cc0 + a4 * 4 + 3][pl]);
        *(ushort4*)(dst + a4 * 4) = o;
    }
}

// ---------------------------------------------------------------------------
// W_eff partial GEMM (bf16 MFMA): wpart[sp][l,n][o][b] = conv_w[l] @ mss[n] over
// K-chunk sp*512..+512. TN form: A=[o][kk], B^T=msst[b][kk]. 128x128 tile, BK=32,
// 4 waves x (4x4) 16x16x32 MFMA tiles. Grid (4 tiles, 12 ln, 8 sk).
__global__ __launch_bounds__(256) void weff_mfma(const ushort* __restrict__ Aw,
                                                 const ushort* __restrict__ Bm,
                                                 float* __restrict__ wpart) {
    const int tile = blockIdx.x;
    const int ln = blockIdx.y;
    const int sp = blockIdx.z;
    const int l = ln >> 2, n = ln & 3;
    const int trow = (tile >> 1) * 128, tcol = (tile & 1) * 128;
    const ushort* A = Aw + (size_t)l * CC * K1;
    const ushort* B = Bm + (size_t)n * CC * K1;
    __shared__ ushort Al[128][40];   // +8 bf16 pad: frag ds_read_b128 2-way max
    __shared__ ushort Bl[128][40];
    const int t = threadIdx.x;
    const int wv = t >> 6, L = t & 63;
    const int wr = (wv >> 1) * 64, wc = (wv & 1) * 64;
    const int l16 = L & 15, q = L >> 4;
    const int r0 = t >> 2, kq0 = (t & 3) * 8;
    f32x4 acc[4][4];
#pragma unroll
    for (int i = 0; i < 4; ++i)
#pragma unroll
        for (int j = 0; j < 4; ++j)
            acc[i][j] = (f32x4){0.f, 0.f, 0.f, 0.f};

    const int kbase = sp * 512;
    for (int kt = 0; kt < 16; ++kt) {
        const int kk = kbase + kt * 32;
        int4 a0 = *(const int4*)(A + (size_t)(trow + r0) * K1 + kk + kq0);
        int4 a1 = *(const int4*)(A + (size_t)(trow + 64 + r0) * K1 + kk + kq0);
        int4 b0 = *(const int4*)(B + (size_t)(tcol + r0) * K1 + kk + kq0);
        int4 b1 = *(const int4*)(B + (size_t)(tcol + 64 + r0) * K1 + kk + kq0);
        __syncthreads();
        *(int4*)&Al[r0][kq0] = a0;
        *(int4*)&Al[64 + r0][kq0] = a1;
        *(int4*)&Bl[r0][kq0] = b0;
        *(int4*)&Bl[64 + r0][kq0] = b1;
        __syncthreads();
        bf16x8 af[4], bfr[4];
#pragma unroll
        for (int i = 0; i < 4; ++i)
            af[i] = *(const bf16x8*)&Al[wr + i * 16 + l16][q * 8];
#pragma unroll
        for (int j = 0; j < 4; ++j)
            bfr[j] = *(const bf16x8*)&Bl[wc + j * 16 + l16][q * 8];
#pragma unroll
        for (int i = 0; i < 4; ++i)
#pragma unroll
            for (int j = 0; j < 4; ++j)
                acc[i][j] = __builtin_amdgcn_mfma_f32_16x16x32_bf16(af[i], bfr[j], acc[i][j], 0, 0, 0);
    }

    float* W = wpart + ((size_t)sp * 12 + ln) * (CC * CC);
#pragma unroll
    for (int i = 0; i < 4; ++i)
#pragma unroll
        for (int j = 0; j < 4; ++j) {
            const int o = trow + wr + i * 16 + q * 4;    // D row = quad*4 + reg
            const int b = tcol + wc + j * 16 + l16;      // D col = lane&15
#pragma unroll
            for (int r = 0; r < 4; ++r)
                W[(size_t)(o + r) * CC + b] = acc[i][j][r];
        }
}

// ---------------------------------------------------------------------------
// Sum 8 split-K partials, fold BN row-scale, emit bf16 Ws[l,n][o][b].
__global__ __launch_bounds__(256) void reduce_kernel(const float* __restrict__ wpart,
                                                     const float* __restrict__ gamma,
                                                     const float* __restrict__ var,
                                                     ushort* __restrict__ Ws) {
    const int idx = (blockIdx.x * 256 + threadIdx.x) * 4;   // over 12*65536
    const int ln = idx >> 16;
    const int l = ln >> 2;
    const int o = (idx >> 8) & 255;
    float4 s = {0.f, 0.f, 0.f, 0.f};
#pragma unroll
    for (int sp = 0; sp < 8; ++sp) {
        float4 v = *(const float4*)(wpart + (size_t)sp * 12 * 65536 + idx);
        s.x += v.x; s.y += v.y; s.z += v.z; s.w += v.w;
    }
    const float sc = gamma[l * CC + o] * rsqrtf(var[l * CC + o] + EPSV);
    ushort4 ob = {f2bf(s.x * sc), f2bf(s.y * sc), f2bf(s.z * sc), f2bf(s.w * sc)};
    *(ushort4*)(Ws + idx) = ob;
}

// ---------------------------------------------------------------------------
// Layer GEMM (bf16 MFMA, TN): yT[p][o] = sum_b xT[p][b] * Ws[o][b]; epilogue
// relu(acc + bias2[o]); writes fp32 out[n][o][p] (float4) + bf16 yT[p][o] (next A).
// 64x64 tile, 4 waves x (2x2). Grid (64 tiles, 4 n).
__global__ __launch_bounds__(256) void layer_mfma(const ushort* __restrict__ xT,
                                                  const ushort* __restrict__ Wsl,
                                                  const float* __restrict__ convb_l,
                                                  const float* __restrict__ gamma_l,
                                                  const float* __restrict__ beta_l,
                                                  const float* __restrict__ mean_l,
                                                  const float* __restrict__ var_l,
                                                  float* __restrict__ outl,
                                                  ushort* __restrict__ xTn) {
    const int n = blockIdx.y;
    const int pt = blockIdx.x & 15, ot = blockIdx.x >> 4;
    const ushort* Axt = xT + (size_t)n * HWP * CC + (size_t)pt * 64 * CC;
    const ushort* Bw  = Wsl + (size_t)n * CC * CC + (size_t)ot * 64 * CC;
    __shared__ ushort Al[64][40];
    __shared__ ushort Bl[64][40];
    const int t = threadIdx.x;
    const int wv = t >> 6, L = t & 63;
    const int wr = (wv >> 1) * 32, wc = (wv & 1) * 32;
    const int l16 = L & 15, q = L >> 4;
    const int r0 = t >> 2, kq0 = (t & 3) * 8;
    f32x4 acc[2][2];
#pragma unroll
    for (int i = 0; i < 2; ++i)
#pragma unroll
        for (int j = 0; j < 2; ++j)
            acc[i][j] = (f32x4){0.f, 0.f, 0.f, 0.f};

    for (int kt = 0; kt < 8; ++kt) {
        const int kk = kt * 32;
        int4 av = *(const int4*)(Axt + (size_t)r0 * CC + kk + kq0);
        int4 bv = *(const int4*)(Bw + (size_t)r0 * CC + kk + kq0);
        __syncthreads();
        *(int4*)&Al[r0][kq0] = av;
        *(int4*)&Bl[r0][kq0] = bv;
        __syncthreads();
        bf16x8 af[2], bfr[2];
#pragma unroll
        for (int i = 0; i < 2; ++i)
            af[i] = *(const bf16x8*)&Al[wr + i * 16 + l16][q * 8];
#pragma unroll
        for (int j = 0; j < 2; ++j)
            bfr[j] = *(const bf16x8*)&Bl[wc + j * 16 + l16][q * 8];
#pragma unroll
        for (int i = 0; i < 2; ++i)
#pragma unroll
            for (int j = 0; j < 2; ++j)
                acc[i][j] = __builtin_amdgcn_mfma_f32_16x16x32_bf16(af[i], bfr[j], acc[i][j], 0, 0, 0);
    }

    float* outn = outl + (size_t)n * CC * HWP;
    ushort* xtn = xTn + (size_t)n * HWP * CC;
#pragma unroll
    for (int i = 0; i < 2; ++i)
#pragma unroll
        for (int j = 0; j < 2; ++j) {
            const int p = pt * 64 + wr + i * 16 + q * 4;   // D row
            const int o = ot * 64 + wc + j * 16 + l16;     // D col
            const float sc = gamma_l[o] * rsqrtf(var_l[o] + EPSV);
            const float b2 = sc * (convb_l[o] - mean_l[o]) + beta_l[o];
            float v0 = fmaxf(acc[i][j][0] + b2, 0.f);
            float v1 = fmaxf(acc[i][j][1] + b2, 0.f);
            float v2 = fmaxf(acc[i][j][2] + b2, 0.f);
            float v3 = fmaxf(acc[i][j][3] + b2, 0.f);
            *(float4*)(outn + (size_t)o * HWP + p) = (float4){v0, v1, v2, v3};
            xtn[(size_t)(p + 0) * CC + o] = f2bf(v0);
            xtn[(size_t)(p + 1) * CC + o] = f2bf(v1);
            xtn[(size_t)(p + 2) * CC + o] = f2bf(v2);
            xtn[(size_t)(p + 3) * CC + o] = f2bf(v3);
        }
}

// ---------------------------------------------------------------------------
extern "C" void kernel_launch(void* const* d_in, const int* in_sizes, int n_in,
                              void* d_out, int out_size, void* d_ws, size_t ws_size,
                              hipStream_t stream) {
    const float* feats  = (const float*)d_in[0];
    const float* adj    = (const float*)d_in[1];
    const float* conv_w = (const float*)d_in[2];
    const float* conv_b = (const float*)d_in[3];
    const float* gamma  = (const float*)d_in[4];
    const float* beta   = (const float*)d_in[5];
    const float* mean   = (const float*)d_in[6];
    const float* var    = (const float*)d_in[7];
    float* out = (float*)d_out;

    // ws layout (bytes):
    //   [0, 64K)            flags
    //   [64K, +6291456)     conv_w bf16 [3][256][4096]
    //   [.., +8388608)      msst bf16   [4][256][4096]
    //   [.., +1572864)      Ws bf16     [12][256][256]
    //   [.., +2097152)      fT0 bf16    [4][1024][256]
    //   [.., +25165824)     wpart fp32  [8][12][256][256]  (aliased by xT1..3 after reduce)
    char* ws = (char*)d_ws;
    uint8_t* flags  = (uint8_t*)ws;
    ushort*  convwb = (ushort*)(ws + 65536);
    ushort*  msst   = (ushort*)(ws + 65536 + 6291456);
    ushort*  Wsb    = (ushort*)(ws + 65536 + 6291456 + 8388608);
    ushort*  fT0    = (ushort*)(ws + 65536 + 6291456 + 8388608 + 1572864);
    float*   wpart  = (float*)(ws + 65536 + 6291456 + 8388608 + 1572864 + 2097152);
    ushort*  xT1    = (ushort*)wpart;                    // safe: wpart consumed by reduce
    ushort*  xT2    = xT1 + (size_t)NB * HWP * CC;
    ushort*  xT3    = xT2 + (size_t)NB * HWP * CC;

    flags_kernel<<<NB * SSL, CC, 0, stream>>>(adj, flags);
    convw_bf16_kernel<<<3072, 256, 0, stream>>>(conv_w, convwb);
    msst_kernel<<<dim3(16, NB), 256, 0, stream>>>(adj, flags, msst);
    featsT_kernel<<<dim3(64, NB), 256, 0, stream>>>(feats, fT0);
    weff_mfma<<<dim3(4, 12, 8), 256, 0, stream>>>(convwb, msst, wpart);
    reduce_kernel<<<768, 256, 0, stream>>>(wpart, gamma, var, Wsb);

    const ushort* xin[3] = {fT0, xT1, xT2};
    ushort* xout[3] = {xT1, xT2, xT3};
    for (int l = 0; l < 3; ++l) {
        layer_mfma<<<dim3(64, NB), 256, 0, stream>>>(
            xin[l], Wsb + (size_t)l * NB * CC * CC,
            conv_b + l * CC, gamma + l * CC, beta + l * CC, mean + l * CC, var + l * CC,
            out + (size_t)l * NB * CC * HWP, xout[l]);
    }
}